// Round 5
// baseline (144.004 us; speedup 1.0000x reference)
//
#include <hip/hip_runtime.h>
#include <hip/hip_bf16.h>
#include <math.h>

#define N_SAMPLES 262144
#define DDIM 64
#define KDIM 64
#define NBLOCKS 2048          // 2048 blocks x 4 waves x 2 tiles x 16 rows
#define NPART (NBLOCKS * 4)   // one partial per wave

#define LOG2PI 1.8378770664093453f
#define PRIOR_LV0 -2.0f
#define IV0 7.389056098930650f  /* exp(2.0) */

// ws layout (floats):
//   [0, 4096)       : Bsw — 16 KB bf16 MFMA coef fragments
//                     frag-set s = kc*4+tile; lane l: 8 bf16 =
//                     B[kc*32 + (l>>4)*8 + j][tile*16 + (l&15)], j=0..7
//                     B[r][k] = r<64 ? P'[k][d=r] : Q[k][d=r-64]
//   [4096, 4160)    : c[k]
//   [4160, 4224)    : logpi[k]
//   [4224, 4224+NPART) : per-wave LSE partials

#define WS_C     4096
#define WS_LPI   4160
#define WS_PART  4224

typedef __attribute__((ext_vector_type(8))) short short8;
typedef __attribute__((ext_vector_type(4))) float floatx4;

static __device__ inline unsigned short f2bf_bits(float f) {
  union { float f; unsigned u; } v; v.f = f;
  unsigned r = v.u + 0x7fffu + ((v.u >> 16) & 1u);  // RNE
  return (unsigned short)(r >> 16);
}

__global__ __launch_bounds__(256) void setup_frags(
    const float* __restrict__ u_noise, const float* __restrict__ phi_logits,
    const float* __restrict__ q_mu, const float* __restrict__ q_logvar,
    const float* __restrict__ pi_logits, float* __restrict__ ws) {
  __shared__ float sPhi[DDIM];
  __shared__ float sR[DDIM];
  __shared__ float sBeta;
  __shared__ float sPart[4][KDIM];
  int tid = threadIdx.x;

  if (tid < 64) {  // exactly wave 0
    int d = tid;
    float u = u_noise[d];
    float g = -__logf(-__logf(u + 1e-9f) + 1e-9f);
    float phi = 1.0f / (1.0f + __expf(-(phi_logits[d] + g)));  // TEMP=1
    sPhi[d] = phi;
    sR[d] = -0.5f * (1.0f - phi) * IV0;

    float betap = -0.5f * (1.0f - phi) * (LOG2PI + PRIOR_LV0);
    #pragma unroll
    for (int o = 1; o < 64; o <<= 1) betap += __shfl_xor(betap, o, 64);
    if (d == 0) sBeta = betap;

    // log(softmax(pi_logits) + 1e-9)
    float l = pi_logits[d];
    float m = l;
    #pragma unroll
    for (int o = 1; o < 64; o <<= 1) m = fmaxf(m, __shfl_xor(m, o, 64));
    float e = __expf(l - m);
    float s = e;
    #pragma unroll
    for (int o = 1; o < 64; o <<= 1) s += __shfl_xor(s, o, 64);
    ws[WS_LPI + d] = __logf(e / s + 1e-9f);
  }
  __syncthreads();

  // c_k partials (256 threads: k = tid&63, d-segment = tid>>6)
  {
    int k = tid & 63, seg = tid >> 6;
    const float* lvp = q_logvar + k * DDIM + seg * 16;
    const float* mup = q_mu + k * DDIM + seg * 16;
    float ap = 0.0f;
    #pragma unroll
    for (int dd = 0; dd < 16; ++dd) {
      int d = seg * 16 + dd;
      float lv = fminf(fmaxf(lvp[dd], -5.0f), 5.0f);
      float mu = mup[dd];
      ap += sPhi[d] * (LOG2PI + lv) + mu * mu * sPhi[d] * __expf(-lv);
    }
    sPart[seg][k] = ap;
  }

  // B-fragments built directly (no fp32 staging round-trip)
  unsigned short* bsw = (unsigned short*)ws;
  #pragma unroll
  for (int p = 0; p < 4; ++p) {
    int pr = p * 256 + tid;      // 0..1023 = frag-set*64 + lane
    int s = pr >> 6, l = pr & 63;
    int kc = s >> 2, tl = s & 3, q = l >> 4, nn = l & 15;
    int k = tl * 16 + nn;
    int dbase = (kc & 1) * 32 + q * 8;
    const float* lvp = q_logvar + k * DDIM + dbase;
    float4 lv0 = *(const float4*)lvp;
    float4 lv1 = *(const float4*)(lvp + 4);
    float lvv[8] = {lv0.x, lv0.y, lv0.z, lv0.w, lv1.x, lv1.y, lv1.z, lv1.w};
    short r8[8];
    if (kc < 2) {  // P' rows
      #pragma unroll
      for (int j = 0; j < 8; ++j) {
        int d = dbase + j;
        float lv = fminf(fmaxf(lvv[j], -5.0f), 5.0f);
        r8[j] = (short)f2bf_bits(-0.5f * sPhi[d] * __expf(-lv) + sR[d]);
      }
    } else {       // Q rows
      const float* mup = q_mu + k * DDIM + dbase;
      float4 mu0 = *(const float4*)mup;
      float4 mu1 = *(const float4*)(mup + 4);
      float muv[8] = {mu0.x, mu0.y, mu0.z, mu0.w, mu1.x, mu1.y, mu1.z, mu1.w};
      #pragma unroll
      for (int j = 0; j < 8; ++j) {
        int d = dbase + j;
        float lv = fminf(fmaxf(lvv[j], -5.0f), 5.0f);
        r8[j] = (short)f2bf_bits(muv[j] * sPhi[d] * __expf(-lv));
      }
    }
    ((short8*)bsw)[pr] = (short8){r8[0], r8[1], r8[2], r8[3],
                                  r8[4], r8[5], r8[6], r8[7]};
  }

  __syncthreads();
  if (tid < 64) {
    float alpha = sPart[0][tid] + sPart[1][tid] + sPart[2][tid] + sPart[3][tid];
    ws[WS_C + tid] = -0.5f * alpha + sBeta;  // c_k
  }
}

// Flat main kernel: 2048 blocks x 4 waves, TWO 16-row tiles per wave.
// X loads for both tiles issued upfront (MLP); coef fragments from L1-hot ws.
// No atomics, no __syncthreads: per-wave partial -> ws[WS_PART + wid].
__global__ __launch_bounds__(256, 4) void gmm_main(
    const float* __restrict__ X, const float* __restrict__ ws,
    float* __restrict__ out) {
  int tid  = threadIdx.x;
  int lane = tid & 63;
  int w    = tid >> 6;
  int n    = lane & 15;   // A-row within tile == C/D column within tile
  int q    = lane >> 4;   // quad
  long wbase = ((long)blockIdx.x * 4 + w) * 32;  // 32 rows per wave

  // ---- issue all 8 X loads upfront
  const float* xr0 = X + (wbase + n) * DDIM;
  const float* xr1 = xr0 + 16 * DDIM;
  float4 raw[2][4];
  raw[0][0] = *(const float4*)(xr0 + q * 8);
  raw[0][1] = *(const float4*)(xr0 + q * 8 + 4);
  raw[0][2] = *(const float4*)(xr0 + 32 + q * 8);
  raw[0][3] = *(const float4*)(xr0 + 32 + q * 8 + 4);
  raw[1][0] = *(const float4*)(xr1 + q * 8);
  raw[1][1] = *(const float4*)(xr1 + q * 8 + 4);
  raw[1][2] = *(const float4*)(xr1 + 32 + q * 8);
  raw[1][3] = *(const float4*)(xr1 + 32 + q * 8 + 4);

  float cb[4], lpi[4];
  #pragma unroll
  for (int t = 0; t < 4; ++t) {
    cb[t]  = ws[WS_C + t * 16 + n];
    lpi[t] = ws[WS_LPI + t * 16 + n];
  }

  const short8* Bf = (const short8*)ws;
  float* lp = out + 1 + DDIM;  // float-offset 65
  float rowacc = 0.0f;

  #pragma unroll
  for (int tt = 0; tt < 2; ++tt) {
    long rbase = wbase + tt * 16;
    // A fragments: kc0 = x^2 lo, kc1 = x^2 hi, kc2 = x lo, kc3 = x hi
    short8 a[4];
    {
      float xa[8] = {raw[tt][0].x, raw[tt][0].y, raw[tt][0].z, raw[tt][0].w,
                     raw[tt][1].x, raw[tt][1].y, raw[tt][1].z, raw[tt][1].w};
      float xb[8] = {raw[tt][2].x, raw[tt][2].y, raw[tt][2].z, raw[tt][2].w,
                     raw[tt][3].x, raw[tt][3].y, raw[tt][3].z, raw[tt][3].w};
      #pragma unroll
      for (int j = 0; j < 8; ++j) {
        a[0][j] = (short)f2bf_bits(xa[j] * xa[j]);
        a[1][j] = (short)f2bf_bits(xb[j] * xb[j]);
        a[2][j] = (short)f2bf_bits(xa[j]);
        a[3][j] = (short)f2bf_bits(xb[j]);
      }
    }
    floatx4 acc[4];
    #pragma unroll
    for (int t = 0; t < 4; ++t) acc[t] = (floatx4){0.f, 0.f, 0.f, 0.f};
    #pragma unroll
    for (int kc = 0; kc < 4; ++kc) {
      #pragma unroll
      for (int t = 0; t < 4; ++t) {
        short8 b = Bf[(kc * 4 + t) * 64 + lane];
        acc[t] = __builtin_amdgcn_mfma_f32_16x16x32_bf16(a[kc], b, acc[t], 0, 0, 0);
      }
    }
    // epilogue: bias + store log_p + LSE reduce
    #pragma unroll
    for (int reg = 0; reg < 4; ++reg) {
      long row = rbase + q * 4 + reg;  // C/D row = quad*4 + reg
      float o0 = acc[0][reg] + cb[0];
      float o1 = acc[1][reg] + cb[1];
      float o2 = acc[2][reg] + cb[2];
      float o3 = acc[3][reg] + cb[3];
      long off = row * KDIM + n;
      lp[off]      = o0;
      lp[off + 16] = o1;
      lp[off + 32] = o2;
      lp[off + 48] = o3;
      float v0 = o0 + lpi[0], v1 = o1 + lpi[1], v2 = o2 + lpi[2], v3 = o3 + lpi[3];
      float m = fmaxf(fmaxf(v0, v1), fmaxf(v2, v3));
      #pragma unroll
      for (int o = 1; o <= 8; o <<= 1) m = fmaxf(m, __shfl_xor(m, o, 64));
      float s = __expf(v0 - m) + __expf(v1 - m) + __expf(v2 - m) + __expf(v3 - m);
      #pragma unroll
      for (int o = 1; o <= 8; o <<= 1) s += __shfl_xor(s, o, 64);
      if (n == 0) rowacc += m + __logf(s);
    }
  }

  // wave partial (lanes 0,16,32,48 hold row sums) -> single store, no sync
  float t2 = (n == 0) ? rowacc : 0.0f;
  t2 += __shfl_xor(t2, 16, 64);
  t2 += __shfl_xor(t2, 32, 64);
  if (lane == 0) {
    float* wsp = (float*)ws;
    wsp[WS_PART + blockIdx.x * 4 + w] = t2;
  }
}

// Final: sum 8192 per-wave partials, kl_phi, q_phi, write out[0], out[1..64].
__global__ __launch_bounds__(256) void finalize_kernel(
    const float* __restrict__ phi_logits, const float* __restrict__ prior_p,
    const float* __restrict__ ws, float* __restrict__ out) {
  __shared__ float sW[4];
  __shared__ float sKl;
  int tid = threadIdx.x;
  int lane = tid & 63, w = tid >> 6;

  float s = 0.0f;
  #pragma unroll
  for (int i = 0; i < NPART / 256; ++i)
    s += ws[WS_PART + i * 256 + tid];
  #pragma unroll
  for (int o = 1; o < 64; o <<= 1) s += __shfl_xor(s, o, 64);
  if (lane == 0) sW[w] = s;

  if (tid < 64) {
    int d = tid;
    float qp = 1.0f / (1.0f + __expf(-phi_logits[d]));
    qp = fminf(fmaxf(qp, 1e-6f), 1.0f - 1e-6f);
    out[1 + d] = qp;
    float pp = fminf(fmaxf(prior_p[d], 1e-6f), 1.0f - 1e-6f);
    float klp = qp * (__logf(qp) - __logf(pp)) +
                (1.0f - qp) * (__logf(1.0f - qp) - __logf(1.0f - pp));
    #pragma unroll
    for (int o = 1; o < 64; o <<= 1) klp += __shfl_xor(klp, o, 64);
    if (d == 0) sKl = klp * (float)N_SAMPLES;
  }
  __syncthreads();
  if (tid == 0) out[0] = sKl - (sW[0] + sW[1] + sW[2] + sW[3]);
}

extern "C" void kernel_launch(void* const* d_in, const int* in_sizes, int n_in,
                              void* d_out, int out_size, void* d_ws, size_t ws_size,
                              hipStream_t stream) {
  const float* X           = (const float*)d_in[0];
  const float* u_noise     = (const float*)d_in[1];
  const float* phi_logits  = (const float*)d_in[2];
  const float* q_mu        = (const float*)d_in[3];
  const float* q_logvar    = (const float*)d_in[4];
  const float* pi_logits   = (const float*)d_in[5];
  const float* prior_p     = (const float*)d_in[6];
  float* out = (float*)d_out;
  float* ws  = (float*)d_ws;

  setup_frags<<<1, 256, 0, stream>>>(u_noise, phi_logits, q_mu, q_logvar,
                                     pi_logits, ws);
  gmm_main<<<NBLOCKS, 256, 0, stream>>>(X, ws, out);
  finalize_kernel<<<1, 256, 0, stream>>>(phi_logits, prior_p, ws, out);
}

// Round 6
// 140.709 us; speedup vs baseline: 1.0234x; 1.0234x over previous
//
#include <hip/hip_runtime.h>
#include <hip/hip_bf16.h>
#include <math.h>

#define N_SAMPLES 262144
#define DDIM 64
#define KDIM 64
#define NBLOCKS 4096          // 4096 blocks x 4 waves x 16 rows
#define NPART (NBLOCKS * 4)   // one partial per wave

#define LOG2PI 1.8378770664093453f
#define PRIOR_LV0 -2.0f
#define IV0 7.389056098930650f  /* exp(2.0) */

// ws layout (floats):
//   [0, 4096)        : Bsw — 16 KB bf16 MFMA coef fragments
//                      frag-set s = kc*4+tile; lane l: 8 bf16 =
//                      B[kc*32 + (l>>4)*8 + j][tile*16 + (l&15)], j=0..7
//                      B[r][k] = r<64 ? P'[k][d=r] : Q[k][d=r-64]
//   [4096, 4160)     : c[k]
//   [4160, 4224)     : logpi[k]
//   [4224, 4224+NPART): per-wave LSE partials
//   [4224+NPART]     : kl_phi * N  (written by setup)

#define WS_C     4096
#define WS_LPI   4160
#define WS_PART  4224
#define WS_KL    (WS_PART + NPART)

typedef __attribute__((ext_vector_type(8))) short short8;
typedef __attribute__((ext_vector_type(4))) float floatx4;

// DPP row_ror:N within each 16-lane row (VALU, ~4-8cyc vs ~30cyc ds shuffle)
#define DPP_ROR(v, N) __int_as_float(__builtin_amdgcn_update_dpp( \
    0, __float_as_int(v), 0x120 + (N), 0xf, 0xf, false))

static __device__ inline unsigned short f2bf_bits(float f) {
  union { float f; unsigned u; } v; v.f = f;
  unsigned r = v.u + 0x7fffu + ((v.u >> 16) & 1u);  // RNE
  return (unsigned short)(r >> 16);
}

__global__ __launch_bounds__(256) void setup_frags(
    const float* __restrict__ u_noise, const float* __restrict__ phi_logits,
    const float* __restrict__ q_mu, const float* __restrict__ q_logvar,
    const float* __restrict__ pi_logits, const float* __restrict__ prior_p,
    float* __restrict__ out, float* __restrict__ ws) {
  __shared__ float sPhi[DDIM];
  __shared__ float sR[DDIM];
  __shared__ float sBeta;
  __shared__ float sPart[4][KDIM];
  int tid = threadIdx.x;

  if (tid < 64) {  // exactly wave 0
    int d = tid;
    float u = u_noise[d];
    float g = -__logf(-__logf(u + 1e-9f) + 1e-9f);
    float phi = 1.0f / (1.0f + __expf(-(phi_logits[d] + g)));  // TEMP=1
    sPhi[d] = phi;
    sR[d] = -0.5f * (1.0f - phi) * IV0;

    float betap = -0.5f * (1.0f - phi) * (LOG2PI + PRIOR_LV0);
    #pragma unroll
    for (int o = 1; o < 64; o <<= 1) betap += __shfl_xor(betap, o, 64);
    if (d == 0) sBeta = betap;

    // log(softmax(pi_logits) + 1e-9)
    float l = pi_logits[d];
    float m = l;
    #pragma unroll
    for (int o = 1; o < 64; o <<= 1) m = fmaxf(m, __shfl_xor(m, o, 64));
    float e = __expf(l - m);
    float s = e;
    #pragma unroll
    for (int o = 1; o < 64; o <<= 1) s += __shfl_xor(s, o, 64);
    ws[WS_LPI + d] = __logf(e / s + 1e-9f);
  } else if (tid >= 64 && tid < 128) {  // wave 1: q_phi + kl_phi
    int d = tid - 64;
    float qp = 1.0f / (1.0f + __expf(-phi_logits[d]));
    qp = fminf(fmaxf(qp, 1e-6f), 1.0f - 1e-6f);
    out[1 + d] = qp;
    float pp = fminf(fmaxf(prior_p[d], 1e-6f), 1.0f - 1e-6f);
    float klp = qp * (__logf(qp) - __logf(pp)) +
                (1.0f - qp) * (__logf(1.0f - qp) - __logf(1.0f - pp));
    #pragma unroll
    for (int o = 1; o < 64; o <<= 1) klp += __shfl_xor(klp, o, 64);
    if (d == 0) ws[WS_KL] = klp * (float)N_SAMPLES;
  }
  __syncthreads();

  // c_k partials (256 threads: k = tid&63, d-segment = tid>>6)
  {
    int k = tid & 63, seg = tid >> 6;
    const float* lvp = q_logvar + k * DDIM + seg * 16;
    const float* mup = q_mu + k * DDIM + seg * 16;
    float ap = 0.0f;
    #pragma unroll
    for (int dd = 0; dd < 16; ++dd) {
      int d = seg * 16 + dd;
      float lv = fminf(fmaxf(lvp[dd], -5.0f), 5.0f);
      float mu = mup[dd];
      ap += sPhi[d] * (LOG2PI + lv) + mu * mu * sPhi[d] * __expf(-lv);
    }
    sPart[seg][k] = ap;
  }

  // B-fragments built directly from params
  unsigned short* bsw = (unsigned short*)ws;
  #pragma unroll
  for (int p = 0; p < 4; ++p) {
    int pr = p * 256 + tid;      // 0..1023 = frag-set*64 + lane
    int s = pr >> 6, l = pr & 63;
    int kc = s >> 2, tl = s & 3, q = l >> 4, nn = l & 15;
    int k = tl * 16 + nn;
    int dbase = (kc & 1) * 32 + q * 8;
    const float* lvp = q_logvar + k * DDIM + dbase;
    float4 lv0 = *(const float4*)lvp;
    float4 lv1 = *(const float4*)(lvp + 4);
    float lvv[8] = {lv0.x, lv0.y, lv0.z, lv0.w, lv1.x, lv1.y, lv1.z, lv1.w};
    short r8[8];
    if (kc < 2) {  // P' rows
      #pragma unroll
      for (int j = 0; j < 8; ++j) {
        int d = dbase + j;
        float lv = fminf(fmaxf(lvv[j], -5.0f), 5.0f);
        r8[j] = (short)f2bf_bits(-0.5f * sPhi[d] * __expf(-lv) + sR[d]);
      }
    } else {       // Q rows
      const float* mup = q_mu + k * DDIM + dbase;
      float4 mu0 = *(const float4*)mup;
      float4 mu1 = *(const float4*)(mup + 4);
      float muv[8] = {mu0.x, mu0.y, mu0.z, mu0.w, mu1.x, mu1.y, mu1.z, mu1.w};
      #pragma unroll
      for (int j = 0; j < 8; ++j) {
        int d = dbase + j;
        float lv = fminf(fmaxf(lvv[j], -5.0f), 5.0f);
        r8[j] = (short)f2bf_bits(muv[j] * sPhi[d] * __expf(-lv));
      }
    }
    ((short8*)bsw)[pr] = (short8){r8[0], r8[1], r8[2], r8[3],
                                  r8[4], r8[5], r8[6], r8[7]};
  }

  __syncthreads();
  if (tid < 64) {
    float alpha = sPart[0][tid] + sPart[1][tid] + sPart[2][tid] + sPart[3][tid];
    ws[WS_C + tid] = -0.5f * alpha + sBeta;  // c_k
  }
}

// Flat main kernel: 4096 blocks x 4 waves, one 16-row tile per wave.
// 8 waves/SIMD occupancy; DPP-based 16-lane LSE reduces (VALU, not DS).
// No atomics, no __syncthreads: per-wave partial -> ws[WS_PART + wid].
__global__ __launch_bounds__(256, 8) void gmm_main(
    const float* __restrict__ X, const float* __restrict__ ws,
    float* __restrict__ out) {
  int tid  = threadIdx.x;
  int lane = tid & 63;
  int w    = tid >> 6;
  int n    = lane & 15;   // A-row within tile == C/D column within tile
  int q    = lane >> 4;   // quad
  long rbase = ((long)blockIdx.x * 4 + w) * 16;

  // ---- X fragment loads: row rbase+n, d in [q*8,q*8+8) and [32+q*8,...)
  const float* xr = X + (rbase + n) * DDIM;
  float4 xa0 = *(const float4*)(xr + q * 8);
  float4 xa1 = *(const float4*)(xr + q * 8 + 4);
  float4 xb0 = *(const float4*)(xr + 32 + q * 8);
  float4 xb1 = *(const float4*)(xr + 32 + q * 8 + 4);

  float cb[4], lpi[4];
  #pragma unroll
  for (int t = 0; t < 4; ++t) {
    cb[t]  = ws[WS_C + t * 16 + n];
    lpi[t] = ws[WS_LPI + t * 16 + n];
  }

  // ---- A fragments: kc0 = x^2 lo, kc1 = x^2 hi, kc2 = x lo, kc3 = x hi
  short8 a[4];
  {
    float xa[8] = {xa0.x, xa0.y, xa0.z, xa0.w, xa1.x, xa1.y, xa1.z, xa1.w};
    float xb[8] = {xb0.x, xb0.y, xb0.z, xb0.w, xb1.x, xb1.y, xb1.z, xb1.w};
    #pragma unroll
    for (int j = 0; j < 8; ++j) {
      a[0][j] = (short)f2bf_bits(xa[j] * xa[j]);
      a[1][j] = (short)f2bf_bits(xb[j] * xb[j]);
      a[2][j] = (short)f2bf_bits(xa[j]);
      a[3][j] = (short)f2bf_bits(xb[j]);
    }
  }

  // ---- MFMA: 4 k-chunks x 4 col-tiles
  const short8* Bf = (const short8*)ws;
  floatx4 acc[4];
  #pragma unroll
  for (int t = 0; t < 4; ++t) acc[t] = (floatx4){0.f, 0.f, 0.f, 0.f};
  #pragma unroll
  for (int kc = 0; kc < 4; ++kc) {
    #pragma unroll
    for (int t = 0; t < 4; ++t) {
      short8 b = Bf[(kc * 4 + t) * 64 + lane];
      acc[t] = __builtin_amdgcn_mfma_f32_16x16x32_bf16(a[kc], b, acc[t], 0, 0, 0);
    }
  }

  // ---- epilogue: bias + store log_p + DPP LSE reduce
  float* lp = out + 1 + DDIM;  // float-offset 65
  float rowacc = 0.0f;
  #pragma unroll
  for (int reg = 0; reg < 4; ++reg) {
    long row = rbase + q * 4 + reg;  // C/D row = quad*4 + reg
    float o0 = acc[0][reg] + cb[0];
    float o1 = acc[1][reg] + cb[1];
    float o2 = acc[2][reg] + cb[2];
    float o3 = acc[3][reg] + cb[3];
    long off = row * KDIM + n;
    lp[off]      = o0;
    lp[off + 16] = o1;
    lp[off + 32] = o2;
    lp[off + 48] = o3;
    float v0 = o0 + lpi[0], v1 = o1 + lpi[1], v2 = o2 + lpi[2], v3 = o3 + lpi[3];
    float m = fmaxf(fmaxf(v0, v1), fmaxf(v2, v3));
    m = fmaxf(m, DPP_ROR(m, 8));
    m = fmaxf(m, DPP_ROR(m, 4));
    m = fmaxf(m, DPP_ROR(m, 2));
    m = fmaxf(m, DPP_ROR(m, 1));
    float s = __expf(v0 - m) + __expf(v1 - m) + __expf(v2 - m) + __expf(v3 - m);
    s += DPP_ROR(s, 8);
    s += DPP_ROR(s, 4);
    s += DPP_ROR(s, 2);
    s += DPP_ROR(s, 1);
    rowacc += m + __logf(s);  // all 16 lanes of the quad-row hold the result
  }
  // rowacc identical within each 16-lane group; sum the 4 groups
  float t2 = rowacc;
  t2 += __shfl_xor(t2, 16, 64);
  t2 += __shfl_xor(t2, 32, 64);
  if (lane == 0) {
    float* wsp = (float*)ws;
    wsp[WS_PART + blockIdx.x * 4 + w] = t2;
  }
}

// Final: sum per-wave partials, combine with kl from ws.
__global__ __launch_bounds__(256) void finalize_kernel(
    const float* __restrict__ ws, float* __restrict__ out) {
  __shared__ float sW[4];
  int tid = threadIdx.x;
  int lane = tid & 63, w = tid >> 6;

  float s = 0.0f;
  #pragma unroll
  for (int i = 0; i < NPART / 256; ++i)
    s += ws[WS_PART + i * 256 + tid];
  #pragma unroll
  for (int o = 1; o < 64; o <<= 1) s += __shfl_xor(s, o, 64);
  if (lane == 0) sW[w] = s;
  __syncthreads();
  if (tid == 0) out[0] = ws[WS_KL] - (sW[0] + sW[1] + sW[2] + sW[3]);
}

extern "C" void kernel_launch(void* const* d_in, const int* in_sizes, int n_in,
                              void* d_out, int out_size, void* d_ws, size_t ws_size,
                              hipStream_t stream) {
  const float* X           = (const float*)d_in[0];
  const float* u_noise     = (const float*)d_in[1];
  const float* phi_logits  = (const float*)d_in[2];
  const float* q_mu        = (const float*)d_in[3];
  const float* q_logvar    = (const float*)d_in[4];
  const float* pi_logits   = (const float*)d_in[5];
  const float* prior_p     = (const float*)d_in[6];
  float* out = (float*)d_out;
  float* ws  = (float*)d_ws;

  setup_frags<<<1, 256, 0, stream>>>(u_noise, phi_logits, q_mu, q_logvar,
                                     pi_logits, prior_p, out, ws);
  gmm_main<<<NBLOCKS, 256, 0, stream>>>(X, ws, out);
  finalize_kernel<<<1, 256, 0, stream>>>(ws, out);
}